// Round 14
// baseline (8805.658 us; speedup 1.0000x reference)
//
#include <hip/hip_runtime.h>

// ============================================================================
// 2-layer tanh RNN, B=32, S=2048, D=H=O=512.
//  r13 = r12 skeleton with a restructured consumer path:
//   (1) 2-deep ping-pong pipelined poll on the FIRST HALF of the h0 fragments
//       (8 dwords/lane, uniform vmcnt(2) waits; in-order vmcnt retires the
//       finishers' older fire-and-forget stores automatically) -> sampling
//       period ~RT/2 and halved poll footprint.
//   (2) second-half h0 + h1(p-2) + z0 issued immediately AFTER first-half
//       detect (h1 is ~1 RT old by then -> fresh), overlapped under the
//       first-half GEMMs; one vmcnt(0); tag-verify + rare re-poll backstop.
//       (r11's version issued h1 BEFORE detect -> guaranteed stale; fixed.)
//   Epoch-tag uniqueness makes half-mixed fetches safe. Stale ping-pong
//   regs kept live past the drain (r10 pattern). Stores = r12 atomics.
// ============================================================================

typedef short v8s __attribute__((ext_vector_type(8)));
typedef int   v4i __attribute__((ext_vector_type(4)));
typedef float v4f __attribute__((ext_vector_type(4)));

#define B_  32
#define S_  2048
#define DH  512
#define SLOT32 16384                      // u32 per ring slot (32 x 512)
#define EPOCH4(q) ((unsigned)(((q) >> 2) & 7))

// ws layout (bytes)
#define BIAS_OFF  0                       // [2][512] f32 (b_ih + b_hh)
#define H0_OFF    8192                    // 4 slots x 64KB packed u32
#define H1_OFF    (H0_OFF + 4 * 65536)
#define WOUT_OFF  (H1_OFF + 4 * 65536)    // w_out bf16 [512][512]
#define WIH0_OFF  (WOUT_OFF + 524288)     // w_ih[0] bf16 [512][512]

#define PART_BYTES (8 * 3 * 4 * 64 * 16)  // 96KB LDS partials

static __device__ __forceinline__ unsigned short f2bf(float f) {  // RNE
  unsigned int u = __builtin_bit_cast(unsigned int, f);
  u += 0x7fffu + ((u >> 16) & 1u);
  return (unsigned short)(u >> 16);
}
static __device__ __forceinline__ float bf2f(unsigned short h) {
  return __builtin_bit_cast(float, ((unsigned int)h) << 16);
}
static __device__ __forceinline__ unsigned packh(float f, unsigned ep) {
  unsigned short hv = f2bf(f);
  unsigned short lv = f2bf(f - bf2f(hv));
  return ((unsigned)hv << 16) | ((unsigned)lv & 0xFFF8u) | ep;
}
static __device__ __forceinline__ v8s pack8(float4 f0, float4 f1) {
  v8s r;
  r[0] = (short)f2bf(f0.x); r[1] = (short)f2bf(f0.y);
  r[2] = (short)f2bf(f0.z); r[3] = (short)f2bf(f0.w);
  r[4] = (short)f2bf(f1.x); r[5] = (short)f2bf(f1.y);
  r[6] = (short)f2bf(f1.z); r[7] = (short)f2bf(f1.w);
  return r;
}
static __device__ __forceinline__ float fast_tanh(float v) {
  float c = fminf(15.f, fmaxf(-15.f, v));
  float e = __expf(2.f * c);
  return (e - 1.f) * __builtin_amdgcn_rcpf(e + 1.f);
}

// ---- device-scope accessors -------------------------------------------------
static __device__ __forceinline__ v4i ld16v(const unsigned* p) {
  v4i r;
  asm volatile("global_load_dwordx4 %0, %1, off sc1"
               : "=v"(r) : "v"(p) : "memory");
  return r;
}
static __device__ __forceinline__ float ld4(const void* p) {  // cached, counted
  float r;
  asm volatile("global_load_dword %0, %1, off"
               : "=v"(r) : "v"(p) : "memory");
  return r;
}
static __device__ __forceinline__ void atom_swap(void* p, unsigned v) {
  asm volatile("global_atomic_swap %0, %1, off"
               :: "v"(p), "v"(v) : "memory");
}
#define WAITN0() do { asm volatile("s_waitcnt vmcnt(0)" ::: "memory"); \
    __builtin_amdgcn_sched_barrier(0); } while (0)
#define WAIT2() do { asm volatile("s_waitcnt vmcnt(2)" ::: "memory"); \
    __builtin_amdgcn_sched_barrier(0); } while (0)

// Full-fragment poll (fallback path): detection + data in one.
static __device__ __forceinline__ void poll_frag(const unsigned* b, unsigned ep,
                                                 bool* bad, v4i* o0, v4i* o1,
                                                 v4i* o2, v4i* o3) {
  v4i a0, a1, a2, a3;
  int t = 0;
  for (;;) {
    a0 = ld16v(b); a1 = ld16v(b + 4); a2 = ld16v(b + 32); a3 = ld16v(b + 36);
    WAITN0();
    if (*bad) break;
    unsigned d = 0;
    #pragma unroll
    for (int j = 0; j < 4; ++j)
      d |= ((unsigned)a0[j] ^ ep) | ((unsigned)a1[j] ^ ep)
         | ((unsigned)a2[j] ^ ep) | ((unsigned)a3[j] ^ ep);
    if (__all((d & 7u) == 0u)) break;
    if (++t > (1 << 15)) { *bad = true; break; }
  }
  *o0 = a0; *o1 = a1; *o2 = a2; *o3 = a3;
}
static __device__ __forceinline__ void unp(v4i a, v4i b, v8s* hi, v8s* lo) {
  v8s h, l;
  #pragma unroll
  for (int j = 0; j < 4; ++j) {
    unsigned ua = (unsigned)a[j], ub = (unsigned)b[j];
    h[j]     = (short)(ua >> 16);   l[j]     = (short)(ua & 0xFFF8u);
    h[4 + j] = (short)(ub >> 16);   l[4 + j] = (short)(ub & 0xFFF8u);
  }
  *hi = h; *lo = l;
}

// ---------------------------------------------------------------------------
__global__ void rnn_init(const float* __restrict__ hidden,
                         const float* __restrict__ b_ih,
                         const float* __restrict__ b_hh,
                         const float* __restrict__ w_out,
                         const float* __restrict__ w_ih,
                         float* __restrict__ bias,
                         unsigned* __restrict__ h0ring,
                         unsigned* __restrict__ h1ring,
                         unsigned short* __restrict__ woutbf,
                         unsigned short* __restrict__ wih0bf) {
  int i = blockIdx.x * blockDim.x + threadIdx.x;
  int nth = gridDim.x * blockDim.x;
  for (int t = i; t < 1024; t += nth) bias[t] = b_ih[t] + b_hh[t];
  for (int t = i; t < 2 * B_ * DH; t += nth) {     // initial h -> slot 3, tag 7
    int l = t >> 14;
    int off = t & 16383;
    unsigned* ring = l ? h1ring : h0ring;
    atom_swap(ring + 3 * SLOT32 + off, packh(hidden[t], 7u));
  }
  for (int t = i; t < 512 * 512; t += nth) {
    woutbf[t] = f2bf(w_out[t]);
    wih0bf[t] = f2bf(w_ih[t]);
  }
}

// ---------------------------------------------------------------------------
// Bulk projection: dst[r][:] = src[r][:] @ wb^T + bias (64 rows/WG, in-place ok)
__global__ __launch_bounds__(512) void proj64(
    const float* __restrict__ src,
    float* __restrict__ dst,
    const unsigned short* __restrict__ wb,
    const float* __restrict__ bias) {
  __shared__ unsigned short lds[64 * 512];
  const int tid = threadIdx.x;
  const int wid = tid >> 6;
  const int lane = tid & 63;
  const size_t row0 = (size_t)blockIdx.x * 64;

  #pragma unroll
  for (int it = 0; it < 8; ++it) {
    int c = it * 512 + tid;
    int row = c >> 6;
    int col8 = c & 63;
    const float4* s4 = (const float4*)(src + (row0 + row) * DH + col8 * 8);
    float4 f0 = s4[0], f1 = s4[1];
    v8s t = pack8(f0, f1);
    int byteoff = row * 1024 + ((col8 * 16) ^ ((row & 7) << 4));
    *(v8s*)((char*)lds + byteoff) = t;
  }
  __syncthreads();

  const int l15 = lane & 15;
  const int kq = (lane >> 4) * 8;

  for (int nt = wid; nt < 32; nt += 8) {
    v4f acc[4];
    #pragma unroll
    for (int mt = 0; mt < 4; ++mt) acc[mt] = (v4f){0.f, 0.f, 0.f, 0.f};
    const unsigned short* wr = wb + (size_t)(nt * 16 + l15) * 512;
    #pragma unroll
    for (int ks = 0; ks < 16; ++ks) {
      int kk = ks * 32 + kq;
      v8s bfrag = *(const v8s*)(wr + kk);
      #pragma unroll
      for (int mt = 0; mt < 4; ++mt) {
        int row = mt * 16 + l15;
        int byteoff = row * 1024 + ((kk * 2) ^ ((row & 7) << 4));
        v8s afrag = *(const v8s*)((char*)lds + byteoff);
        acc[mt] = __builtin_amdgcn_mfma_f32_16x16x32_bf16(afrag, bfrag, acc[mt], 0, 0, 0);
      }
    }
    float bo = bias[nt * 16 + l15];
    #pragma unroll
    for (int mt = 0; mt < 4; ++mt)
      #pragma unroll
      for (int r = 0; r < 4; ++r) {
        int row = mt * 16 + (lane >> 4) * 4 + r;
        int col = nt * 16 + l15;
        dst[(row0 + row) * DH + col] = acc[mt][r] + bo;
      }
  }
}

// ---------------------------------------------------------------------------
// Fused persistent kernel. wg = mh*8 + fs. 8 waves = 8 K-eighths.
__global__ __launch_bounds__(512) void rnn_fused(
    const float* __restrict__ z0,     // d_out: Z0 (overwritten by dout)
    const float* __restrict__ w_ih,
    const float* __restrict__ w_hh,
    const float* __restrict__ bias,
    unsigned* __restrict__ h0ring,
    unsigned* __restrict__ h1ring,
    float* __restrict__ dout) {
  extern __shared__ char smem[];
  v4f* part = (v4f*)smem;               // [8][3][4][64]

  const int wg = blockIdx.x;
  const int mh = wg >> 3;               // batch half
  const int fs = wg & 7;                // feature slice (64 feats)

  const int tid = threadIdx.x;
  const int wid = tid >> 6;             // K-eighth
  const int lane = tid & 63;
  const int l15 = lane & 15;
  const int kq = (lane >> 4) * 8;
  const int q4 = (lane >> 4) * 4;

  // resident weights: wfrag[g][n][ks], g: {w_hh0, w_ih1, w_hh1}
  v8s wfrag[3][4][2];
  {
    const float* wsrcs[3] = { w_hh, w_ih + 512 * 512, w_hh + 512 * 512 };
    #pragma unroll
    for (int g = 0; g < 3; ++g)
      #pragma unroll
      for (int n = 0; n < 4; ++n)
        #pragma unroll
        for (int ks = 0; ks < 2; ++ks) {
          const float* srow = wsrcs[g] +
              (size_t)(fs * 64 + n * 16 + l15) * 512 + wid * 64 + ks * 32 + kq;
          wfrag[g][n][ks] = pack8(*(const float4*)srow, *(const float4*)(srow + 4));
        }
  }
  const int nf = wid & 3;               // finisher n-tile (wid<4)
  const float bias1v = bias[512 + fs * 64 + nf * 16 + l15];
  const size_t abase = (size_t)(mh * 16 + l15) * 512 + wid * 64 + kq;
  const int featf = fs * 64 + nf * 16 + l15;

  bool bad = false;

  for (int p = 0; p <= S_; ++p) {
    const unsigned ep0 = (p == 0) ? 7u : EPOCH4(p - 1);
    const unsigned ep1 = (p == 1) ? 7u : EPOCH4(p - 2);
    const unsigned* h0b = h0ring + (size_t)((p + 3) & 3) * SLOT32 + abase;
    const unsigned* h1b = h1ring + (size_t)((p + 2) & 3) * SLOT32 + abase;

    // ---- 2-deep ping-pong pipelined poll on h0 first half -----------------
    // vmcnt is in-order: any older fire-and-forget stores retire before the
    // wait unblocks, so uniform vmcnt(2) is correct on all waves.
    v4i Pa0 = ld16v(h0b); v4i Pa1 = ld16v(h0b + 4);
    v4i Pb0 = ld16v(h0b); v4i Pb1 = ld16v(h0b + 4);
    v4i F0, F1;
    {
      int t = 0;
      for (;;) {
        WAIT2();                                   // round A complete
        unsigned d = 0;
        #pragma unroll
        for (int j = 0; j < 4; ++j)
          d |= ((unsigned)Pa0[j] ^ ep0) | ((unsigned)Pa1[j] ^ ep0);
        if (__all((d & 7u) == 0u) || bad) { F0 = Pa0; F1 = Pa1; break; }
        Pa0 = ld16v(h0b); Pa1 = ld16v(h0b + 4);    // reissue A
        WAIT2();                                   // round B complete
        d = 0;
        #pragma unroll
        for (int j = 0; j < 4; ++j)
          d |= ((unsigned)Pb0[j] ^ ep0) | ((unsigned)Pb1[j] ^ ep0);
        if (__all((d & 7u) == 0u)) { F0 = Pb0; F1 = Pb1; break; }
        Pb0 = ld16v(h0b); Pb1 = ld16v(h0b + 4);    // reissue B
        if (++t > (1 << 15)) { bad = true; F0 = Pb0; F1 = Pb1; break; }
      }
    }

    // ---- post-detect: issue 2nd half + h1 + z0, overlap under GEMMs -------
    v4i A2 = ld16v(h0b + 32), A3 = ld16v(h0b + 36);
    v4i B0, B1, B2, B3;
    if (p >= 1) {
      B0 = ld16v(h1b); B1 = ld16v(h1b + 4);
      B2 = ld16v(h1b + 32); B3 = ld16v(h1b + 36);
    }
    float zp[4];
    if (wid < 4) {
      const int pz = (p < S_) ? p : (S_ - 1);
      #pragma unroll
      for (int r = 0; r < 4; ++r)
        zp[r] = ld4(z0 + ((size_t)(mh * 16 + q4 + r) * S_ + pz) * DH + featf);
    }

    v8s h0h0, h0l0;
    unp(F0, F1, &h0h0, &h0l0);

    v4f acc0[4], acc1[4], acc2[4];
    #pragma unroll
    for (int n = 0; n < 4; ++n) {
      acc0[n] = (v4f){0.f, 0.f, 0.f, 0.f};
      acc1[n] = (v4f){0.f, 0.f, 0.f, 0.f};
      acc2[n] = (v4f){0.f, 0.f, 0.f, 0.f};
    }
    #pragma unroll
    for (int n = 0; n < 4; ++n) {                   // first-half GEMMs (ks=0)
      acc0[n] = __builtin_amdgcn_mfma_f32_16x16x32_bf16(h0h0, wfrag[0][n][0], acc0[n], 0, 0, 0);
      acc0[n] = __builtin_amdgcn_mfma_f32_16x16x32_bf16(h0l0, wfrag[0][n][0], acc0[n], 0, 0, 0);
      acc1[n] = __builtin_amdgcn_mfma_f32_16x16x32_bf16(h0h0, wfrag[1][n][0], acc1[n], 0, 0, 0);
      acc1[n] = __builtin_amdgcn_mfma_f32_16x16x32_bf16(h0l0, wfrag[1][n][0], acc1[n], 0, 0, 0);
    }

    WAITN0();                                       // drain stale + A2/A3 + B + zp
    asm volatile("" :: "v"(Pa0), "v"(Pa1), "v"(Pb0), "v"(Pb1));  // keep-alive

    {                                               // verify 2nd-half tags
      unsigned d = 0;
      #pragma unroll
      for (int j = 0; j < 4; ++j)
        d |= ((unsigned)A2[j] ^ ep0) | ((unsigned)A3[j] ^ ep0);
      if (!__all((d & 7u) == 0u)) {                 // rare: re-poll 2nd half
        int t = 0;
        for (;;) {
          A2 = ld16v(h0b + 32); A3 = ld16v(h0b + 36);
          WAITN0();
          if (bad) break;
          d = 0;
          #pragma unroll
          for (int j = 0; j < 4; ++j)
            d |= ((unsigned)A2[j] ^ ep0) | ((unsigned)A3[j] ^ ep0);
          if (__all((d & 7u) == 0u)) break;
          if (++t > (1 << 15)) { bad = true; break; }
        }
      }
    }
    v8s h0h1, h0l1;
    unp(A2, A3, &h0h1, &h0l1);
    #pragma unroll
    for (int n = 0; n < 4; ++n) {                   // second-half GEMMs (ks=1)
      acc0[n] = __builtin_amdgcn_mfma_f32_16x16x32_bf16(h0h1, wfrag[0][n][1], acc0[n], 0, 0, 0);
      acc0[n] = __builtin_amdgcn_mfma_f32_16x16x32_bf16(h0l1, wfrag[0][n][1], acc0[n], 0, 0, 0);
      acc1[n] = __builtin_amdgcn_mfma_f32_16x16x32_bf16(h0h1, wfrag[1][n][1], acc1[n], 0, 0, 0);
      acc1[n] = __builtin_amdgcn_mfma_f32_16x16x32_bf16(h0l1, wfrag[1][n][1], acc1[n], 0, 0, 0);
    }

    if (p >= 1) {                                   // verify h1 tags; GEMM2
      unsigned d = 0;
      #pragma unroll
      for (int j = 0; j < 4; ++j)
        d |= ((unsigned)B0[j] ^ ep1) | ((unsigned)B1[j] ^ ep1)
           | ((unsigned)B2[j] ^ ep1) | ((unsigned)B3[j] ^ ep1);
      if (!__all((d & 7u) == 0u))
        poll_frag(h1b, ep1, &bad, &B0, &B1, &B2, &B3);
      v8s h1h0, h1l0, h1h1, h1l1;
      unp(B0, B1, &h1h0, &h1l0);
      unp(B2, B3, &h1h1, &h1l1);
      #pragma unroll
      for (int n = 0; n < 4; ++n) {
        acc2[n] = __builtin_amdgcn_mfma_f32_16x16x32_bf16(h1h0, wfrag[2][n][0], acc2[n], 0, 0, 0);
        acc2[n] = __builtin_amdgcn_mfma_f32_16x16x32_bf16(h1l0, wfrag[2][n][0], acc2[n], 0, 0, 0);
        acc2[n] = __builtin_amdgcn_mfma_f32_16x16x32_bf16(h1h1, wfrag[2][n][1], acc2[n], 0, 0, 0);
        acc2[n] = __builtin_amdgcn_mfma_f32_16x16x32_bf16(h1l1, wfrag[2][n][1], acc2[n], 0, 0, 0);
      }
    }

    // ---- K-reduction partials ---------------------------------------------
    #pragma unroll
    for (int n = 0; n < 4; ++n) {
      part[((wid * 3 + 0) * 4 + n) * 64 + lane] = acc0[n];
      part[((wid * 3 + 1) * 4 + n) * 64 + lane] = acc1[n];
      part[((wid * 3 + 2) * 4 + n) * 64 + lane] = acc2[n];
    }
    __syncthreads();

    // ---- finishers: reduce, tanh, pack+tag, fire-and-forget stores --------
    if (wid < 4) {
      v4f s0 = {0.f,0.f,0.f,0.f}, s1 = {0.f,0.f,0.f,0.f}, s2 = {0.f,0.f,0.f,0.f};
      #pragma unroll
      for (int w = 0; w < 8; ++w) {
        s0 += part[((w * 3 + 0) * 4 + nf) * 64 + lane];
        s1 += part[((w * 3 + 1) * 4 + nf) * 64 + lane];
        s2 += part[((w * 3 + 2) * 4 + nf) * 64 + lane];
      }
      float h0v[4], h1v[4];
      #pragma unroll
      for (int r = 0; r < 4; ++r) {
        h0v[r] = fast_tanh(zp[r] + s0[r]);
        h1v[r] = fast_tanh(s1[r] + s2[r] + bias1v);
      }
      if (p < S_) {                                 // h0(p) FIRST (critical)
        const unsigned ep = EPOCH4(p);
        unsigned* dst = h0ring + (size_t)(p & 3) * SLOT32;
        #pragma unroll
        for (int r = 0; r < 4; ++r)
          atom_swap(dst + (size_t)(mh * 16 + q4 + r) * 512 + featf,
                    packh(h0v[r], ep));
      }
      if (p >= 1) {                                 // then h1(p-1) + dout
        const unsigned ep = EPOCH4(p - 1);
        unsigned* dst = h1ring + (size_t)((p - 1) & 3) * SLOT32;
        #pragma unroll
        for (int r = 0; r < 4; ++r) {
          atom_swap(dst + (size_t)(mh * 16 + q4 + r) * 512 + featf,
                    packh(h1v[r], ep));
          dout[((size_t)(mh * 16 + q4 + r) * S_ + (p - 1)) * DH + featf] = h1v[r];
        }
      }
    }
    __syncthreads();   // keep LDS partials stable until finishers consumed them
  }
}

// ---------------------------------------------------------------------------
extern "C" void kernel_launch(void* const* d_in, const int* in_sizes, int n_in,
                              void* d_out, int out_size, void* d_ws, size_t ws_size,
                              hipStream_t stream) {
  const float* x      = (const float*)d_in[0];
  const float* hidden = (const float*)d_in[1];
  const float* w_ih   = (const float*)d_in[2];
  const float* w_hh   = (const float*)d_in[3];
  const float* b_ih   = (const float*)d_in[4];
  const float* b_hh   = (const float*)d_in[5];
  const float* w_out  = (const float*)d_in[6];
  const float* b_out  = (const float*)d_in[7];
  float* out = (float*)d_out;

  char* wsb = (char*)d_ws;
  float* bias            = (float*)(wsb + BIAS_OFF);
  unsigned* h0ring       = (unsigned*)(wsb + H0_OFF);
  unsigned* h1ring       = (unsigned*)(wsb + H1_OFF);
  unsigned short* woutbf = (unsigned short*)(wsb + WOUT_OFF);
  unsigned short* wih0bf = (unsigned short*)(wsb + WIH0_OFF);

  rnn_init<<<256, 256, 0, stream>>>(hidden, b_ih, b_hh, w_out, w_ih,
                                    bias, h0ring, h1ring, woutbf, wih0bf);
  // Z0 = x @ w_ih0^T + (b_ih0 + b_hh0) -> d_out
  proj64<<<(B_ * S_) / 64, 512, 0, stream>>>(x, out, wih0bf, bias);
  rnn_fused<<<16, 512, PART_BYTES, stream>>>(out, w_ih, w_hh, bias,
                                             h0ring, h1ring, out);
  // out = h1 @ w_out^T + b_out (in place)
  proj64<<<(B_ * S_) / 64, 512, 0, stream>>>(out, out, woutbf, b_out);
}